// Round 16
// baseline (263.010 us; speedup 1.0000x reference)
//
#include <hip/hip_runtime.h>

#define N_NODES 100000
#define E_EDGES 600000
#define LATDIM 128
#define HEAD 4
#define HDIM 32

#define SCAN_NB 98          // 98 scan blocks x 1024 elems >= N_NODES
#define CSR_BLOCKS 256      // fused csr kernel grid (<= 1 block/CU, co-resident)

typedef _Float16 f16x8 __attribute__((ext_vector_type(8)));
typedef _Float16 f16x2 __attribute__((ext_vector_type(2)));
typedef float    f32x4 __attribute__((ext_vector_type(4)));

__device__ __forceinline__ unsigned f32_to_bf16_rne(float x) {
    unsigned u = __float_as_uint(x);
    u += 0x7fffu + ((u >> 16) & 1u);   // round to nearest even
    return u >> 16;
}

// 4-dim f16 dot with f32 accumulate: k01,k23 vs q01,q23 (f16 pairs in u32).
__device__ __forceinline__ float dot4_f16(unsigned k01, unsigned k23,
                                          unsigned q01, unsigned q23) {
#if defined(__has_builtin)
#if __has_builtin(__builtin_amdgcn_fdot2)
    float r = __builtin_amdgcn_fdot2(__builtin_bit_cast(f16x2, k01),
                                     __builtin_bit_cast(f16x2, q01), 0.f, false);
    return  __builtin_amdgcn_fdot2(__builtin_bit_cast(f16x2, k23),
                                   __builtin_bit_cast(f16x2, q23), r, false);
#else
    f16x2 a = __builtin_bit_cast(f16x2, k01), b = __builtin_bit_cast(f16x2, q01);
    f16x2 c = __builtin_bit_cast(f16x2, k23), d = __builtin_bit_cast(f16x2, q23);
    return (float)a[0]*(float)b[0] + (float)a[1]*(float)b[1]
         + (float)c[0]*(float)d[0] + (float)c[1]*(float)d[1];
#endif
#else
    f16x2 a = __builtin_bit_cast(f16x2, k01), b = __builtin_bit_cast(f16x2, q01);
    f16x2 c = __builtin_bit_cast(f16x2, k23), d = __builtin_bit_cast(f16x2, q23);
    return (float)a[0]*(float)b[0] + (float)a[1]*(float)b[1]
         + (float)c[0]*(float)d[0] + (float)c[1]*(float)d[1];
#endif
}

// ---------------------------------------------------------------------------
// Weight prep + workspace zeroing. W[k][c] f32 -> WT[m][c][k] f16.
// Also zeroes counts and the 128-word state array (incl. the grid-barrier
// counter state[100]) — graph replays require re-zeroing every launch.
// ---------------------------------------------------------------------------
__global__ __launch_bounds__(256) void wprep_kernel(
    const float* __restrict__ qT, const float* __restrict__ kT,
    const float* __restrict__ vT,
    unsigned short* __restrict__ WT,
    int* __restrict__ counts, unsigned* __restrict__ state)
{
    int g = blockIdx.x * 256 + threadIdx.x;

    for (int i = g; i < N_NODES; i += SCAN_NB * 256) counts[i] = 0;
    if (g < 128) state[g] = 0u;

    if (g >= 3072) return;
    int m    = g >> 10;          // 0..2
    int rem  = g & 1023;
    int c    = rem >> 3;         // 0..127
    int k0   = (rem & 7) * 16;   // 0..112
    const float* W = (m == 0) ? qT : (m == 1) ? kT : vT;

    unsigned short hv[16];
    #pragma unroll
    for (int j = 0; j < 16; ++j) {
        _Float16 h = (_Float16)W[(size_t)(k0 + j) * 128 + c];   // RNE cvt
        hv[j] = __builtin_bit_cast(unsigned short, h);
    }
    size_t off = (size_t)m * 16384 + (size_t)c * 128 + k0;
    *(uint4*)(WT + off)     = *(const uint4*)&hv[0];
    *(uint4*)(WT + off + 8) = *(const uint4*)&hv[8];
}

// ---------------------------------------------------------------------------
// Kernel A v11 (proven best): f16 MFMA shell. Q f16 out; KV word =
// {k f16 | v bf16 << 16}; A staged f16 then B double-buffered R0<->R1;
// 32 KiB LDS, 8 barriers/block, named scalar prefetch regs; hist at tail.
// ---------------------------------------------------------------------------
__global__ __launch_bounds__(256) void qkv_mfma_kernel(
    const float* __restrict__ embeds,
    const unsigned short* __restrict__ WT,
    const int* __restrict__ rows,
    int* __restrict__ counts,
    unsigned short* __restrict__ Qh, unsigned* __restrict__ KV)
{
    __shared__ __align__(16) char smem[32768];
    char* R0 = smem;               // A (stage+hoist), then B buffer
    char* R1 = smem + 16384;       // B buffer

    const int tid = threadIdx.x;
    const int rowBase = blockIdx.x * 64;

    uint4 pb0, pb1, pb2, pb3;      // named scalars: cannot be promoted

#define PF(MN, HN) do {                                                          \
        const char* _s = (const char*)(WT + (size_t)(MN) * 16384                 \
                                          + (size_t)(HN) * 8192);                \
        pb0 = *(const uint4*)(_s + (size_t)(0 * 256 + tid) * 16);                \
        pb1 = *(const uint4*)(_s + (size_t)(1 * 256 + tid) * 16);                \
        pb2 = *(const uint4*)(_s + (size_t)(2 * 256 + tid) * 16);                \
        pb3 = *(const uint4*)(_s + (size_t)(3 * 256 + tid) * 16);                \
    } while (0)

#define COMMIT(R) do {                                                           \
        { int _i = 0 * 256 + tid; int _c = _i >> 4;                              \
          int _s = (_c * 256 + (_i & 15) * 16) ^ ((_c & 7) << 4);                \
          *(uint4*)((R) + _s) = pb0; }                                           \
        { int _i = 1 * 256 + tid; int _c = _i >> 4;                              \
          int _s = (_c * 256 + (_i & 15) * 16) ^ ((_c & 7) << 4);                \
          *(uint4*)((R) + _s) = pb1; }                                           \
        { int _i = 2 * 256 + tid; int _c = _i >> 4;                              \
          int _s = (_c * 256 + (_i & 15) * 16) ^ ((_c & 7) << 4);                \
          *(uint4*)((R) + _s) = pb2; }                                           \
        { int _i = 3 * 256 + tid; int _c = _i >> 4;                              \
          int _s = (_c * 256 + (_i & 15) * 16) ^ ((_c & 7) << 4);                \
          *(uint4*)((R) + _s) = pb3; }                                           \
    } while (0)

#define MFMA_M(ACC, R) do {                                                      \
        _Pragma("unroll")                                                        \
        for (int kk = 0; kk < 4; ++kk) {                                         \
            _Pragma("unroll")                                                    \
            for (int n = 0; n < 4; ++n) {                                        \
                int col  = n * 16 + lrow;                                        \
                int byte = (col * 256 + kk * 64 + kg * 16) ^ ((lrow & 7) << 4);  \
                f16x8 b = __builtin_bit_cast(f16x8, *(const uint4*)((R) + byte)); \
                ACC[n] = __builtin_amdgcn_mfma_f32_16x16x32_f16(a[kk], b, ACC[n], 0, 0, 0); \
            }                                                                    \
        }                                                                        \
    } while (0)

#define ZACC(ACC) f32x4 ACC[4] = { {0.f,0.f,0.f,0.f}, {0.f,0.f,0.f,0.f},         \
                                   {0.f,0.f,0.f,0.f}, {0.f,0.f,0.f,0.f} }

#define STORE_Q(ACC, H) do {                                                     \
        _Pragma("unroll")                                                        \
        for (int n = 0; n < 4; ++n)                                              \
        _Pragma("unroll")                                                        \
        for (int j = 0; j < 4; ++j) {                                            \
            int gr  = rowBase + wv * 16 + kg * 4 + j;                            \
            int col = (H) * 64 + n * 16 + lrow;                                  \
            if (gr < N_NODES)                                                    \
                Qh[(size_t)gr * 128 + col] =                                     \
                    __builtin_bit_cast(unsigned short, (_Float16)ACC[n][j]);     \
        }                                                                        \
    } while (0)

#define STORE_KV(ACC, H) do {                                                    \
        _Pragma("unroll")                                                        \
        for (int n = 0; n < 4; ++n)                                              \
        _Pragma("unroll")                                                        \
        for (int j = 0; j < 4; ++j) {                                            \
            int gr  = rowBase + wv * 16 + kg * 4 + j;                            \
            int col = (H) * 64 + n * 16 + lrow;                                  \
            if (gr < N_NODES) {                                                  \
                unsigned pk = (unsigned)__builtin_bit_cast(unsigned short,       \
                                  (_Float16)kreg[n][j])                          \
                            | (f32_to_bf16_rne(ACC[n][j]) << 16);                \
                KV[(size_t)gr * 128 + col] = pk;                                 \
            }                                                                    \
        }                                                                        \
    } while (0)

    // ---- prefetch B(m0,h0): overlaps the whole A-stage ----
    PF(0, 0);

    // ---- stage A: embeds f32 -> f16, swizzled into R0 (16 KiB) ----
    #pragma unroll
    for (int it = 0; it < 4; ++it) {
        int idx = it * 256 + tid;          // 16B chunk id, 0..1023
        int r   = idx >> 4;                // row 0..63
        int c16 = idx & 15;                // 16B chunk within row (8 f16)
        int gr  = rowBase + r;
        float4 u0 = make_float4(0.f, 0.f, 0.f, 0.f), u1 = u0;
        if (gr < N_NODES) {
            const float* p = embeds + (size_t)gr * 128 + c16 * 8;
            u0 = *(const float4*)p;
            u1 = *(const float4*)(p + 4);
        }
        f16x8 v;
        v[0] = (_Float16)u0.x; v[1] = (_Float16)u0.y;
        v[2] = (_Float16)u0.z; v[3] = (_Float16)u0.w;
        v[4] = (_Float16)u1.x; v[5] = (_Float16)u1.y;
        v[6] = (_Float16)u1.z; v[7] = (_Float16)u1.w;
        int byte = (r * 256 + c16 * 16) ^ ((r & 7) << 4);
        *(uint4*)(R0 + byte) = __builtin_bit_cast(uint4, v);
    }
    __syncthreads();                                   // sync1: A staged

    const int lane = tid & 63;
    const int wv   = tid >> 6;         // 0..3 (wave -> 16-row tile)
    const int lrow = lane & 15;
    const int kg   = lane >> 4;        // 0..3

    // ---- phase X: hoist A frags from R0; commit B(m0,h0) -> R1 ----
    f16x8 a[4];
    {
        const int arow = wv * 16 + lrow;
        #pragma unroll
        for (int kk = 0; kk < 4; ++kk) {
            int byte = (arow * 256 + kk * 64 + kg * 16) ^ ((lrow & 7) << 4);
            a[kk] = __builtin_bit_cast(f16x8, *(const uint4*)(R0 + byte));
        }
    }
    COMMIT(R1);
    __syncthreads();                                   // sync2: R1 ready, A dead

    f32x4 kreg[4];

    // ---- p0: Q h0 (R1); PF m1,h0 -> commit R0 ----
    {
        PF(1, 0); ZACC(acc);
        MFMA_M(acc, R1);
        STORE_Q(acc, 0);
        COMMIT(R0); __syncthreads();
    }
    // ---- p1: K h0 (R0); PF m2,h0 -> commit R1 ----
    {
        PF(2, 0); ZACC(acc);
        MFMA_M(acc, R0);
        kreg[0] = acc[0]; kreg[1] = acc[1]; kreg[2] = acc[2]; kreg[3] = acc[3];
        COMMIT(R1); __syncthreads();
    }
    // ---- p2: V h0 -> KV (R1); PF m0,h1 -> commit R0 ----
    {
        PF(0, 1); ZACC(acc);
        MFMA_M(acc, R1);
        STORE_KV(acc, 0);
        COMMIT(R0); __syncthreads();
    }
    // ---- p3: Q h1 (R0); PF m1,h1 -> commit R1 ----
    {
        PF(1, 1); ZACC(acc);
        MFMA_M(acc, R0);
        STORE_Q(acc, 1);
        COMMIT(R1); __syncthreads();
    }
    // ---- p4: K h1 (R1); PF m2,h1 -> commit R0 ----
    {
        PF(2, 1); ZACC(acc);
        MFMA_M(acc, R1);
        kreg[0] = acc[0]; kreg[1] = acc[1]; kreg[2] = acc[2]; kreg[3] = acc[3];
        COMMIT(R0); __syncthreads();
    }
    // ---- p5: V h1 -> KV (R0) ----
    {
        ZACC(acc);
        MFMA_M(acc, R0);
        STORE_KV(acc, 1);
    }

    // ---- fused edge histogram at the tail (fire-and-forget atomics) ----
    for (int e = blockIdx.x * 256 + tid; e < E_EDGES; e += gridDim.x * 256)
        atomicAdd(&counts[rows[e]], 1);

#undef PF
#undef COMMIT
#undef MFMA_M
#undef ZACC
#undef STORE_Q
#undef STORE_KV
}

// ---------------------------------------------------------------------------
// Fused CSR kernel: scan (decoupled lookback, wave-parallel window) +
// GRID BARRIER + scatter. 256 blocks x 256 thr -> <=1 block/CU, all
// co-resident (same trust level as the lookback spin itself).
// Blocks 0..97 scan their 1024-node slice and write starts/cursor; all
// 256 blocks rendezvous on state[100]; then all grid-stride the scatter.
// Removes one dispatch boundary vs separate scan+scatter launches.
// state word = (sum<<2)|st, st: 0=invalid 1=aggregate 2=prefix.
// ---------------------------------------------------------------------------
__global__ __launch_bounds__(256) void csr_kernel(
    const int* __restrict__ counts, int* __restrict__ starts,
    int* __restrict__ cursor, unsigned* __restrict__ state,
    const int* __restrict__ rows, const int* __restrict__ cols,
    int* __restrict__ csrCols)
{
    __shared__ int s[256];
    __shared__ int bcast;
    int b = blockIdx.x, t = threadIdx.x;

    if (b < SCAN_NB) {
        int base = b * 1024 + t * 4;
        int v0 = (base + 0 < N_NODES) ? counts[base + 0] : 0;
        int v1 = (base + 1 < N_NODES) ? counts[base + 1] : 0;
        int v2 = (base + 2 < N_NODES) ? counts[base + 2] : 0;
        int v3 = (base + 3 < N_NODES) ? counts[base + 3] : 0;
        int local = v0 + v1 + v2 + v3;
        s[t] = local;
        __syncthreads();
        for (int off = 1; off < 256; off <<= 1) {
            int x = (t >= off) ? s[t - off] : 0;
            __syncthreads();
            s[t] += x;
            __syncthreads();
        }
        int incl  = s[t];
        int excl  = incl - local;
        int total = s[255];

        // ---- publish aggregate (or prefix for block 0) ----
        if (t == 0) {
            if (b == 0) {
                atomicExch(&state[0], ((unsigned)total << 2) | 2u);
                bcast = 0;
            } else {
                atomicExch(&state[b], ((unsigned)total << 2) | 1u);
            }
        }

        // ---- wave-parallel lookback (wave 0 only) ----
        if (b > 0 && t < 64) {
            int sum  = 0;
            int wbase = b - 1;
            while (true) {
                int idx = wbase - t;                    // lane t looks at idx
                unsigned w = (idx >= 0)
                           ? atomicAdd(&state[idx], 0u) // atomic load
                           : 2u;                        // virtual prefix, val 0
                unsigned st = w & 3u;
                unsigned long long m0 = __ballot(st == 0u);
                unsigned long long m2 = __ballot(st == 2u);
                int p = m2 ? (int)(__ffsll((unsigned long long)m2) - 1) : 64;
                unsigned long long below =
                    (p < 64) ? ((1ull << p) - 1ull) : ~0ull;
                bool clean = ((m0 & below) == 0ull) && (p < 64 ? true : m0 == 0ull);
                if (clean) {
                    int contrib = (t <= p) ? (int)(w >> 2) : 0;
                    contrib += __shfl_down(contrib, 32);
                    contrib += __shfl_down(contrib, 16);
                    contrib += __shfl_down(contrib, 8);
                    contrib += __shfl_down(contrib, 4);
                    contrib += __shfl_down(contrib, 2);
                    contrib += __shfl_down(contrib, 1);
                    if (t == 0) sum += contrib;
                    if (p < 64) break;                  // found a prefix
                    wbase -= 64;                        // slide the window
                }
                // else: an unpublished block below the prefix -> retry window
            }
            if (t == 0) {
                atomicExch(&state[b], ((unsigned)(sum + total) << 2) | 2u);
                bcast = sum;
            }
        }
        __syncthreads();
        int e = excl + bcast;
        if (base + 0 < N_NODES) { starts[base + 0] = e;                cursor[base + 0] = e; }
        if (base + 1 < N_NODES) { starts[base + 1] = e + v0;           cursor[base + 1] = e + v0; }
        if (base + 2 < N_NODES) { starts[base + 2] = e + v0 + v1;      cursor[base + 2] = e + v0 + v1; }
        if (base + 3 < N_NODES) { starts[base + 3] = e + v0 + v1 + v2; cursor[base + 3] = e + v0 + v1 + v2; }
    }

    // ---- grid barrier: all cursor writes visible before any scatter ----
    __threadfence();
    __syncthreads();
    if (t == 0) {
        atomicAdd(&state[100], 1u);
        while (atomicAdd(&state[100], 0u) < (unsigned)CSR_BLOCKS) { }
    }
    __syncthreads();

    // ---- scatter (grid-stride; independent iterations pipeline) ----
    for (int e = b * 256 + t; e < E_EDGES; e += CSR_BLOCKS * 256) {
        int pos = atomicAdd(&cursor[rows[e]], 1);
        csrCols[pos] = cols[e];
    }
}

// ---------------------------------------------------------------------------
// Kernel B v11 (proven best): depth-2 pipelined attention + aggregation.
// 2 nodes/wave, 32 lanes/node, 4 dims/lane; per-edge load = one uint4 of
// 4 interleaved words {k f16 | v bf16<<16}; dot via v_dot2_f32_f16.
// Named A/B register batches (rule #20), predicated 4-edge tail.
// ---------------------------------------------------------------------------
__global__ __launch_bounds__(256) void att_agg_kernel(
    const unsigned short* __restrict__ Qh, const unsigned* __restrict__ KV,
    const float* __restrict__ filt,
    const int* __restrict__ starts, const int* __restrict__ counts,
    const int* __restrict__ csrCols,
    float* __restrict__ out)
{
    int t = threadIdx.x;
    int node = blockIdx.x * 8 + (t >> 5);
    if (node >= N_NODES) return;
    int lane = t & 31;
    int h = lane >> 3;

    uint2 qp = *(const uint2*)(Qh + (size_t)node * 128 + lane * 4);  // 4 f16
    int s    = starts[node];
    int cnt  = counts[node];
    int last = cnt - 1;

    float norm = 0.f;
    float ax = 0.f, ay = 0.f, az = 0.f, aw = 0.f;

    int   a_c0, a_c1, a_c2, a_c3,  b_c0, b_c1, b_c2, b_c3;
    float a_f0, a_f1, a_f2, a_f3,  b_f0, b_f1, b_f2, b_f3;
    uint4 a_k0, a_k1, a_k2, a_k3,  b_k0, b_k1, b_k2, b_k3;

#define LOADB(P, I) do {                                                        \
        int _i1 = (I) + 1 < last ? (I) + 1 : last;                              \
        int _i2 = (I) + 2 < last ? (I) + 2 : last;                              \
        int _i3 = (I) + 3 < last ? (I) + 3 : last;                              \
        P##_c0 = csrCols[s + (I)];  P##_c1 = csrCols[s + _i1];                  \
        P##_c2 = csrCols[s + _i2];  P##_c3 = csrCols[s + _i3];                  \
        P##_k0 = ((const uint4*)KV)[(size_t)P##_c0 * 32 + lane];                \
        P##_k1 = ((const uint4*)KV)[(size_t)P##_c1 * 32 + lane];                \
        P##_k2 = ((const uint4*)KV)[(size_t)P##_c2 * 32 + lane];                \
        P##_k3 = ((const uint4*)KV)[(size_t)P##_c3 * 32 + lane];                \
        P##_f0 = filt[P##_c0 * HEAD + h];  P##_f1 = filt[P##_c1 * HEAD + h];    \
        P##_f2 = filt[P##_c2 * HEAD + h];  P##_f3 = filt[P##_c3 * HEAD + h];    \
    } while (0)

#define EDGE(KVU, F, VALID) {                                                   \
        unsigned k01 = ((KVU).x & 0xffffu) | ((KVU).y << 16);                   \
        unsigned k23 = ((KVU).z & 0xffffu) | ((KVU).w << 16);                   \
        float p = dot4_f16(k01, k23, qp.x, qp.y);                               \
        float v0f = __uint_as_float((KVU).x & 0xffff0000u);                     \
        float v1f = __uint_as_float((KVU).y & 0xffff0000u);                     \
        float v2f = __uint_as_float((KVU).z & 0xffff0000u);                     \
        float v3f = __uint_as_float((KVU).w & 0xffff0000u);                     \
        p += __shfl_xor(p, 1);                                                  \
        p += __shfl_xor(p, 2);                                                  \
        p += __shfl_xor(p, 4);                                                  \
        float w = __expf(fminf(fmaxf(p, -10.f), 10.f) + (F));                   \
        w = (VALID) ? w : 0.f;                                                  \
        norm += w;                                                              \
        ax += w * v0f; ay += w * v1f; az += w * v2f; aw += w * v3f; }

#define CONSUME(P, I) do {                                                      \
        bool _m1 = (I) + 1 <= last;                                             \
        bool _m2 = (I) + 2 <= last;                                             \
        bool _m3 = (I) + 3 <= last;                                             \
        EDGE(P##_k0, P##_f0, true);                                             \
        EDGE(P##_k1, P##_f1, _m1);                                              \
        EDGE(P##_k2, P##_f2, _m2);                                              \
        EDGE(P##_k3, P##_f3, _m3);                                              \
    } while (0)

    if (cnt > 0) {
        LOADB(a, 0);
        int i = 0;
        while (true) {
            if (i + 4 < cnt) LOADB(b, i + 4);       // prefetch next batch
            CONSUME(a, i);
            i += 4;
            if (i >= cnt) break;
            if (i + 4 < cnt) LOADB(a, i + 4);       // prefetch next batch
            CONSUME(b, i);
            i += 4;
            if (i >= cnt) break;
        }
    }
#undef LOADB
#undef EDGE
#undef CONSUME

    float inv = 1.0f / (norm + 1e-8f);
    ((float4*)(out + (size_t)node * 128))[lane] =
        make_float4(ax * inv, ay * inv, az * inv, aw * inv);
}

// ---------------------------------------------------------------------------
extern "C" void kernel_launch(void* const* d_in, const int* in_sizes, int n_in,
                              void* d_out, int out_size, void* d_ws, size_t ws_size,
                              hipStream_t stream) {
    const float* embeds = (const float*)d_in[0];
    const float* qT     = (const float*)d_in[1];
    const float* kT     = (const float*)d_in[2];
    const float* vT     = (const float*)d_in[3];
    const float* filt   = (const float*)d_in[4];
    const int*   rows   = (const int*)d_in[5];
    const int*   cols   = (const int*)d_in[6];
    float*       out    = (float*)d_out;

    // Workspace: Qh: N*128 f16 | KV: N*128 u32 | counts,starts,cursor: N i32 |
    //            csrCols: E i32 | state: 128 u32
    unsigned short* Qh = (unsigned short*)d_ws;
    unsigned* KV   = (unsigned*)(Qh + (size_t)N_NODES * 128);
    int* counts    = (int*)(KV + (size_t)N_NODES * 128);
    int* starts    = counts + N_NODES;
    int* cursor    = starts + N_NODES;
    int* csrCols   = cursor + N_NODES;
    unsigned* state = (unsigned*)(csrCols + E_EDGES);

    // f16 weight plane ALIASES the csrCols region (96 KiB of 2.34 MiB).
    // Stream-ordered safe: wprep+qkv complete before csr writes csrCols.
    unsigned short* WT = (unsigned short*)csrCols;

    wprep_kernel<<<SCAN_NB, 256, 0, stream>>>(qT, kT, vT, WT, counts, state);
    qkv_mfma_kernel<<<(N_NODES + 63) / 64, 256, 0, stream>>>(
        embeds, WT, rows, counts, Qh, KV);
    csr_kernel<<<CSR_BLOCKS, 256, 0, stream>>>(
        counts, starts, cursor, state, rows, cols, csrCols);
    att_agg_kernel<<<(N_NODES + 7) / 8, 256, 0, stream>>>(
        Qh, KV, filt, starts, counts, csrCols, out);
}

// Round 17
// 240.665 us; speedup vs baseline: 1.0928x; 1.0928x over previous
//
#include <hip/hip_runtime.h>

#define N_NODES 100000
#define E_EDGES 600000
#define LATDIM 128
#define HEAD 4
#define HDIM 32

#define SCAN_NB 98          // 98 blocks x 1024 elems >= N_NODES

typedef _Float16 f16x8 __attribute__((ext_vector_type(8)));
typedef _Float16 f16x2 __attribute__((ext_vector_type(2)));
typedef float    f32x4 __attribute__((ext_vector_type(4)));

__device__ __forceinline__ unsigned f32_to_bf16_rne(float x) {
    unsigned u = __float_as_uint(x);
    u += 0x7fffu + ((u >> 16) & 1u);   // round to nearest even
    return u >> 16;
}

// 4-dim f16 dot with f32 accumulate: k01,k23 vs q01,q23 (f16 pairs in u32).
__device__ __forceinline__ float dot4_f16(unsigned k01, unsigned k23,
                                          unsigned q01, unsigned q23) {
#if defined(__has_builtin)
#if __has_builtin(__builtin_amdgcn_fdot2)
    float r = __builtin_amdgcn_fdot2(__builtin_bit_cast(f16x2, k01),
                                     __builtin_bit_cast(f16x2, q01), 0.f, false);
    return  __builtin_amdgcn_fdot2(__builtin_bit_cast(f16x2, k23),
                                   __builtin_bit_cast(f16x2, q23), r, false);
#else
    f16x2 a = __builtin_bit_cast(f16x2, k01), b = __builtin_bit_cast(f16x2, q01);
    f16x2 c = __builtin_bit_cast(f16x2, k23), d = __builtin_bit_cast(f16x2, q23);
    return (float)a[0]*(float)b[0] + (float)a[1]*(float)b[1]
         + (float)c[0]*(float)d[0] + (float)c[1]*(float)d[1];
#endif
#else
    f16x2 a = __builtin_bit_cast(f16x2, k01), b = __builtin_bit_cast(f16x2, q01);
    f16x2 c = __builtin_bit_cast(f16x2, k23), d = __builtin_bit_cast(f16x2, q23);
    return (float)a[0]*(float)b[0] + (float)a[1]*(float)b[1]
         + (float)c[0]*(float)d[0] + (float)c[1]*(float)d[1];
#endif
}

// ---------------------------------------------------------------------------
// Weight prep + workspace zeroing. W[k][c] f32 -> WT[m][c][k] f16.
// ---------------------------------------------------------------------------
__global__ __launch_bounds__(256) void wprep_kernel(
    const float* __restrict__ qT, const float* __restrict__ kT,
    const float* __restrict__ vT,
    unsigned short* __restrict__ WT,
    int* __restrict__ counts, unsigned* __restrict__ state)
{
    int g = blockIdx.x * 256 + threadIdx.x;

    // zero counts + scan state (graph replays => re-zero every launch)
    for (int i = g; i < N_NODES; i += SCAN_NB * 256) counts[i] = 0;
    if (g < 128) state[g] = 0u;

    if (g >= 3072) return;
    int m    = g >> 10;          // 0..2
    int rem  = g & 1023;
    int c    = rem >> 3;         // 0..127
    int k0   = (rem & 7) * 16;   // 0..112
    const float* W = (m == 0) ? qT : (m == 1) ? kT : vT;

    unsigned short hv[16];
    #pragma unroll
    for (int j = 0; j < 16; ++j) {
        _Float16 h = (_Float16)W[(size_t)(k0 + j) * 128 + c];   // RNE cvt
        hv[j] = __builtin_bit_cast(unsigned short, h);
    }
    size_t off = (size_t)m * 16384 + (size_t)c * 128 + k0;
    *(uint4*)(WT + off)     = *(const uint4*)&hv[0];
    *(uint4*)(WT + off + 8) = *(const uint4*)&hv[8];
}

// ---------------------------------------------------------------------------
// Kernel A v11 (proven best): f16 MFMA shell. Q f16 out; KV word =
// {k f16 | v bf16 << 16}; A staged f16 then B double-buffered R0<->R1;
// 32 KiB LDS, 8 barriers/block, named scalar prefetch regs; hist at tail.
// ---------------------------------------------------------------------------
__global__ __launch_bounds__(256) void qkv_mfma_kernel(
    const float* __restrict__ embeds,
    const unsigned short* __restrict__ WT,
    const int* __restrict__ rows,
    int* __restrict__ counts,
    unsigned short* __restrict__ Qh, unsigned* __restrict__ KV)
{
    __shared__ __align__(16) char smem[32768];
    char* R0 = smem;               // A (stage+hoist), then B buffer
    char* R1 = smem + 16384;       // B buffer

    const int tid = threadIdx.x;
    const int rowBase = blockIdx.x * 64;

    uint4 pb0, pb1, pb2, pb3;      // named scalars: cannot be promoted

#define PF(MN, HN) do {                                                          \
        const char* _s = (const char*)(WT + (size_t)(MN) * 16384                 \
                                          + (size_t)(HN) * 8192);                \
        pb0 = *(const uint4*)(_s + (size_t)(0 * 256 + tid) * 16);                \
        pb1 = *(const uint4*)(_s + (size_t)(1 * 256 + tid) * 16);                \
        pb2 = *(const uint4*)(_s + (size_t)(2 * 256 + tid) * 16);                \
        pb3 = *(const uint4*)(_s + (size_t)(3 * 256 + tid) * 16);                \
    } while (0)

#define COMMIT(R) do {                                                           \
        { int _i = 0 * 256 + tid; int _c = _i >> 4;                              \
          int _s = (_c * 256 + (_i & 15) * 16) ^ ((_c & 7) << 4);                \
          *(uint4*)((R) + _s) = pb0; }                                           \
        { int _i = 1 * 256 + tid; int _c = _i >> 4;                              \
          int _s = (_c * 256 + (_i & 15) * 16) ^ ((_c & 7) << 4);                \
          *(uint4*)((R) + _s) = pb1; }                                           \
        { int _i = 2 * 256 + tid; int _c = _i >> 4;                              \
          int _s = (_c * 256 + (_i & 15) * 16) ^ ((_c & 7) << 4);                \
          *(uint4*)((R) + _s) = pb2; }                                           \
        { int _i = 3 * 256 + tid; int _c = _i >> 4;                              \
          int _s = (_c * 256 + (_i & 15) * 16) ^ ((_c & 7) << 4);                \
          *(uint4*)((R) + _s) = pb3; }                                           \
    } while (0)

#define MFMA_M(ACC, R) do {                                                      \
        _Pragma("unroll")                                                        \
        for (int kk = 0; kk < 4; ++kk) {                                         \
            _Pragma("unroll")                                                    \
            for (int n = 0; n < 4; ++n) {                                        \
                int col  = n * 16 + lrow;                                        \
                int byte = (col * 256 + kk * 64 + kg * 16) ^ ((lrow & 7) << 4);  \
                f16x8 b = __builtin_bit_cast(f16x8, *(const uint4*)((R) + byte)); \
                ACC[n] = __builtin_amdgcn_mfma_f32_16x16x32_f16(a[kk], b, ACC[n], 0, 0, 0); \
            }                                                                    \
        }                                                                        \
    } while (0)

#define ZACC(ACC) f32x4 ACC[4] = { {0.f,0.f,0.f,0.f}, {0.f,0.f,0.f,0.f},         \
                                   {0.f,0.f,0.f,0.f}, {0.f,0.f,0.f,0.f} }

#define STORE_Q(ACC, H) do {                                                     \
        _Pragma("unroll")                                                        \
        for (int n = 0; n < 4; ++n)                                              \
        _Pragma("unroll")                                                        \
        for (int j = 0; j < 4; ++j) {                                            \
            int gr  = rowBase + wv * 16 + kg * 4 + j;                            \
            int col = (H) * 64 + n * 16 + lrow;                                  \
            if (gr < N_NODES)                                                    \
                Qh[(size_t)gr * 128 + col] =                                     \
                    __builtin_bit_cast(unsigned short, (_Float16)ACC[n][j]);     \
        }                                                                        \
    } while (0)

#define STORE_KV(ACC, H) do {                                                    \
        _Pragma("unroll")                                                        \
        for (int n = 0; n < 4; ++n)                                              \
        _Pragma("unroll")                                                        \
        for (int j = 0; j < 4; ++j) {                                            \
            int gr  = rowBase + wv * 16 + kg * 4 + j;                            \
            int col = (H) * 64 + n * 16 + lrow;                                  \
            if (gr < N_NODES) {                                                  \
                unsigned pk = (unsigned)__builtin_bit_cast(unsigned short,       \
                                  (_Float16)kreg[n][j])                          \
                            | (f32_to_bf16_rne(ACC[n][j]) << 16);                \
                KV[(size_t)gr * 128 + col] = pk;                                 \
            }                                                                    \
        }                                                                        \
    } while (0)

    // ---- prefetch B(m0,h0): overlaps the whole A-stage ----
    PF(0, 0);

    // ---- stage A: embeds f32 -> f16, swizzled into R0 (16 KiB) ----
    #pragma unroll
    for (int it = 0; it < 4; ++it) {
        int idx = it * 256 + tid;          // 16B chunk id, 0..1023
        int r   = idx >> 4;                // row 0..63
        int c16 = idx & 15;                // 16B chunk within row (8 f16)
        int gr  = rowBase + r;
        float4 u0 = make_float4(0.f, 0.f, 0.f, 0.f), u1 = u0;
        if (gr < N_NODES) {
            const float* p = embeds + (size_t)gr * 128 + c16 * 8;
            u0 = *(const float4*)p;
            u1 = *(const float4*)(p + 4);
        }
        f16x8 v;
        v[0] = (_Float16)u0.x; v[1] = (_Float16)u0.y;
        v[2] = (_Float16)u0.z; v[3] = (_Float16)u0.w;
        v[4] = (_Float16)u1.x; v[5] = (_Float16)u1.y;
        v[6] = (_Float16)u1.z; v[7] = (_Float16)u1.w;
        int byte = (r * 256 + c16 * 16) ^ ((r & 7) << 4);
        *(uint4*)(R0 + byte) = __builtin_bit_cast(uint4, v);
    }
    __syncthreads();                                   // sync1: A staged

    const int lane = tid & 63;
    const int wv   = tid >> 6;         // 0..3 (wave -> 16-row tile)
    const int lrow = lane & 15;
    const int kg   = lane >> 4;        // 0..3

    // ---- phase X: hoist A frags from R0; commit B(m0,h0) -> R1 ----
    f16x8 a[4];
    {
        const int arow = wv * 16 + lrow;
        #pragma unroll
        for (int kk = 0; kk < 4; ++kk) {
            int byte = (arow * 256 + kk * 64 + kg * 16) ^ ((lrow & 7) << 4);
            a[kk] = __builtin_bit_cast(f16x8, *(const uint4*)(R0 + byte));
        }
    }
    COMMIT(R1);
    __syncthreads();                                   // sync2: R1 ready, A dead

    f32x4 kreg[4];

    // ---- p0: Q h0 (R1); PF m1,h0 -> commit R0 ----
    {
        PF(1, 0); ZACC(acc);
        MFMA_M(acc, R1);
        STORE_Q(acc, 0);
        COMMIT(R0); __syncthreads();
    }
    // ---- p1: K h0 (R0); PF m2,h0 -> commit R1 ----
    {
        PF(2, 0); ZACC(acc);
        MFMA_M(acc, R0);
        kreg[0] = acc[0]; kreg[1] = acc[1]; kreg[2] = acc[2]; kreg[3] = acc[3];
        COMMIT(R1); __syncthreads();
    }
    // ---- p2: V h0 -> KV (R1); PF m0,h1 -> commit R0 ----
    {
        PF(0, 1); ZACC(acc);
        MFMA_M(acc, R1);
        STORE_KV(acc, 0);
        COMMIT(R0); __syncthreads();
    }
    // ---- p3: Q h1 (R0); PF m1,h1 -> commit R1 ----
    {
        PF(1, 1); ZACC(acc);
        MFMA_M(acc, R0);
        STORE_Q(acc, 1);
        COMMIT(R1); __syncthreads();
    }
    // ---- p4: K h1 (R1); PF m2,h1 -> commit R0 ----
    {
        PF(2, 1); ZACC(acc);
        MFMA_M(acc, R1);
        kreg[0] = acc[0]; kreg[1] = acc[1]; kreg[2] = acc[2]; kreg[3] = acc[3];
        COMMIT(R0); __syncthreads();
    }
    // ---- p5: V h1 -> KV (R0) ----
    {
        ZACC(acc);
        MFMA_M(acc, R0);
        STORE_KV(acc, 1);
    }

    // ---- fused edge histogram at the tail (fire-and-forget atomics) ----
    for (int e = blockIdx.x * 256 + tid; e < E_EDGES; e += gridDim.x * 256)
        atomicAdd(&counts[rows[e]], 1);

#undef PF
#undef COMMIT
#undef MFMA_M
#undef ZACC
#undef STORE_Q
#undef STORE_KV
}

// ---------------------------------------------------------------------------
// Single-pass exclusive scan, decoupled lookback, WAVE-PARALLEL window (r12).
// state word = (sum<<2)|st, st: 0=invalid 1=aggregate 2=prefix.
// ---------------------------------------------------------------------------
__global__ __launch_bounds__(256) void scan_lb_kernel(
    const int* __restrict__ counts, int* __restrict__ starts,
    int* __restrict__ cursor, unsigned* __restrict__ state)
{
    __shared__ int s[256];
    __shared__ int bcast;
    int b = blockIdx.x, t = threadIdx.x;
    int base = b * 1024 + t * 4;
    int v0 = (base + 0 < N_NODES) ? counts[base + 0] : 0;
    int v1 = (base + 1 < N_NODES) ? counts[base + 1] : 0;
    int v2 = (base + 2 < N_NODES) ? counts[base + 2] : 0;
    int v3 = (base + 3 < N_NODES) ? counts[base + 3] : 0;
    int local = v0 + v1 + v2 + v3;
    s[t] = local;
    __syncthreads();
    for (int off = 1; off < 256; off <<= 1) {
        int x = (t >= off) ? s[t - off] : 0;
        __syncthreads();
        s[t] += x;
        __syncthreads();
    }
    int incl  = s[t];
    int excl  = incl - local;
    int total = s[255];

    // ---- publish aggregate (or prefix for block 0) ----
    if (t == 0) {
        if (b == 0) {
            atomicExch(&state[0], ((unsigned)total << 2) | 2u);
            bcast = 0;
        } else {
            atomicExch(&state[b], ((unsigned)total << 2) | 1u);
        }
    }

    // ---- wave-parallel lookback (wave 0 only) ----
    if (b > 0 && t < 64) {
        int sum  = 0;
        int wbase = b - 1;
        while (true) {
            int idx = wbase - t;                        // lane t looks at idx
            unsigned w = (idx >= 0)
                       ? atomicAdd(&state[idx], 0u)     // atomic load
                       : 2u;                            // virtual prefix, val 0
            unsigned st = w & 3u;
            unsigned long long m0 = __ballot(st == 0u);
            unsigned long long m2 = __ballot(st == 2u);
            int p = m2 ? (int)(__ffsll((unsigned long long)m2) - 1) : 64;
            unsigned long long below =
                (p < 64) ? ((1ull << p) - 1ull) : ~0ull;
            bool clean = ((m0 & below) == 0ull) && (p < 64 ? true : m0 == 0ull);
            if (clean) {
                int contrib = (t <= p) ? (int)(w >> 2) : 0;
                contrib += __shfl_down(contrib, 32);
                contrib += __shfl_down(contrib, 16);
                contrib += __shfl_down(contrib, 8);
                contrib += __shfl_down(contrib, 4);
                contrib += __shfl_down(contrib, 2);
                contrib += __shfl_down(contrib, 1);
                if (t == 0) sum += contrib;
                if (p < 64) break;                      // found a prefix
                wbase -= 64;                            // slide the window
            }
            // else: an unpublished block below the prefix -> retry window
        }
        if (t == 0) {
            atomicExch(&state[b], ((unsigned)(sum + total) << 2) | 2u);
            bcast = sum;
        }
    }
    __syncthreads();
    int e = excl + bcast;
    if (base + 0 < N_NODES) { starts[base + 0] = e;                cursor[base + 0] = e; }
    if (base + 1 < N_NODES) { starts[base + 1] = e + v0;           cursor[base + 1] = e + v0; }
    if (base + 2 < N_NODES) { starts[base + 2] = e + v0 + v1;      cursor[base + 2] = e + v0 + v1; }
    if (base + 3 < N_NODES) { starts[base + 3] = e + v0 + v1 + v2; cursor[base + 3] = e + v0 + v1 + v2; }
}

__global__ __launch_bounds__(256) void scatter_kernel(
    const int* __restrict__ rows, const int* __restrict__ cols,
    int* __restrict__ cursor, int* __restrict__ csrCols)
{
    int e = blockIdx.x * 256 + threadIdx.x;
    if (e >= E_EDGES) return;
    int pos = atomicAdd(&cursor[rows[e]], 1);
    csrCols[pos] = cols[e];
}

// ---------------------------------------------------------------------------
// Kernel B v11 (proven best): depth-2 pipelined attention + aggregation.
// 2 nodes/wave, 32 lanes/node, 4 dims/lane; per-edge load = one uint4 of
// 4 interleaved words {k f16 | v bf16<<16}; dot via v_dot2_f32_f16.
// Named A/B register batches (rule #20), predicated 4-edge tail.
// ---------------------------------------------------------------------------
__global__ __launch_bounds__(256) void att_agg_kernel(
    const unsigned short* __restrict__ Qh, const unsigned* __restrict__ KV,
    const float* __restrict__ filt,
    const int* __restrict__ starts, const int* __restrict__ counts,
    const int* __restrict__ csrCols,
    float* __restrict__ out)
{
    int t = threadIdx.x;
    int node = blockIdx.x * 8 + (t >> 5);
    if (node >= N_NODES) return;
    int lane = t & 31;
    int h = lane >> 3;

    uint2 qp = *(const uint2*)(Qh + (size_t)node * 128 + lane * 4);  // 4 f16
    int s    = starts[node];
    int cnt  = counts[node];
    int last = cnt - 1;

    float norm = 0.f;
    float ax = 0.f, ay = 0.f, az = 0.f, aw = 0.f;

    int   a_c0, a_c1, a_c2, a_c3,  b_c0, b_c1, b_c2, b_c3;
    float a_f0, a_f1, a_f2, a_f3,  b_f0, b_f1, b_f2, b_f3;
    uint4 a_k0, a_k1, a_k2, a_k3,  b_k0, b_k1, b_k2, b_k3;

#define LOADB(P, I) do {                                                        \
        int _i1 = (I) + 1 < last ? (I) + 1 : last;                              \
        int _i2 = (I) + 2 < last ? (I) + 2 : last;                              \
        int _i3 = (I) + 3 < last ? (I) + 3 : last;                              \
        P##_c0 = csrCols[s + (I)];  P##_c1 = csrCols[s + _i1];                  \
        P##_c2 = csrCols[s + _i2];  P##_c3 = csrCols[s + _i3];                  \
        P##_k0 = ((const uint4*)KV)[(size_t)P##_c0 * 32 + lane];                \
        P##_k1 = ((const uint4*)KV)[(size_t)P##_c1 * 32 + lane];                \
        P##_k2 = ((const uint4*)KV)[(size_t)P##_c2 * 32 + lane];                \
        P##_k3 = ((const uint4*)KV)[(size_t)P##_c3 * 32 + lane];                \
        P##_f0 = filt[P##_c0 * HEAD + h];  P##_f1 = filt[P##_c1 * HEAD + h];    \
        P##_f2 = filt[P##_c2 * HEAD + h];  P##_f3 = filt[P##_c3 * HEAD + h];    \
    } while (0)

#define EDGE(KVU, F, VALID) {                                                   \
        unsigned k01 = ((KVU).x & 0xffffu) | ((KVU).y << 16);                   \
        unsigned k23 = ((KVU).z & 0xffffu) | ((KVU).w << 16);                   \
        float p = dot4_f16(k01, k23, qp.x, qp.y);                               \
        float v0f = __uint_as_float((KVU).x & 0xffff0000u);                     \
        float v1f = __uint_as_float((KVU).y & 0xffff0000u);                     \
        float v2f = __uint_as_float((KVU).z & 0xffff0000u);                     \
        float v3f = __uint_as_float((KVU).w & 0xffff0000u);                     \
        p += __shfl_xor(p, 1);                                                  \
        p += __shfl_xor(p, 2);                                                  \
        p += __shfl_xor(p, 4);                                                  \
        float w = __expf(fminf(fmaxf(p, -10.f), 10.f) + (F));                   \
        w = (VALID) ? w : 0.f;                                                  \
        norm += w;                                                              \
        ax += w * v0f; ay += w * v1f; az += w * v2f; aw += w * v3f; }

#define CONSUME(P, I) do {                                                      \
        bool _m1 = (I) + 1 <= last;                                             \
        bool _m2 = (I) + 2 <= last;                                             \
        bool _m3 = (I) + 3 <= last;                                             \
        EDGE(P##_k0, P##_f0, true);                                             \
        EDGE(P##_k1, P##_f1, _m1);                                              \
        EDGE(P##_k2, P##_f2, _m2);                                              \
        EDGE(P##_k3, P##_f3, _m3);                                              \
    } while (0)

    if (cnt > 0) {
        LOADB(a, 0);
        int i = 0;
        while (true) {
            if (i + 4 < cnt) LOADB(b, i + 4);       // prefetch next batch
            CONSUME(a, i);
            i += 4;
            if (i >= cnt) break;
            if (i + 4 < cnt) LOADB(a, i + 4);       // prefetch next batch
            CONSUME(b, i);
            i += 4;
            if (i >= cnt) break;
        }
    }
#undef LOADB
#undef EDGE
#undef CONSUME

    float inv = 1.0f / (norm + 1e-8f);
    ((float4*)(out + (size_t)node * 128))[lane] =
        make_float4(ax * inv, ay * inv, az * inv, aw * inv);
}

// ---------------------------------------------------------------------------
extern "C" void kernel_launch(void* const* d_in, const int* in_sizes, int n_in,
                              void* d_out, int out_size, void* d_ws, size_t ws_size,
                              hipStream_t stream) {
    const float* embeds = (const float*)d_in[0];
    const float* qT     = (const float*)d_in[1];
    const float* kT     = (const float*)d_in[2];
    const float* vT     = (const float*)d_in[3];
    const float* filt   = (const float*)d_in[4];
    const int*   rows   = (const int*)d_in[5];
    const int*   cols   = (const int*)d_in[6];
    float*       out    = (float*)d_out;

    // Workspace: Qh: N*128 f16 | KV: N*128 u32 | counts,starts,cursor: N i32 |
    //            csrCols: E i32 | state: 128 u32
    unsigned short* Qh = (unsigned short*)d_ws;
    unsigned* KV   = (unsigned*)(Qh + (size_t)N_NODES * 128);
    int* counts    = (int*)(KV + (size_t)N_NODES * 128);
    int* starts    = counts + N_NODES;
    int* cursor    = starts + N_NODES;
    int* csrCols   = cursor + N_NODES;
    unsigned* state = (unsigned*)(csrCols + E_EDGES);

    // f16 weight plane ALIASES the csrCols region (96 KiB of 2.34 MiB).
    // Stream-ordered safe: wprep+qkv complete before scatter writes csrCols.
    unsigned short* WT = (unsigned short*)csrCols;

    wprep_kernel<<<SCAN_NB, 256, 0, stream>>>(qT, kT, vT, WT, counts, state);
    qkv_mfma_kernel<<<(N_NODES + 63) / 64, 256, 0, stream>>>(
        embeds, WT, rows, counts, Qh, KV);
    scan_lb_kernel<<<SCAN_NB, 256, 0, stream>>>(counts, starts, cursor, state);
    scatter_kernel<<<(E_EDGES + 255) / 256, 256, 0, stream>>>(rows, cols, cursor, csrCols);
    att_agg_kernel<<<(N_NODES + 7) / 8, 256, 0, stream>>>(
        Qh, KV, filt, starts, counts, csrCols, out);
}